// Round 1
// baseline (379.511 us; speedup 1.0000x reference)
//
#include <hip/hip_runtime.h>
#include <stdint.h>

// ProposalLayerSoft: 3x3x3 NMS + per-batch top-10 + coord epilogue.
// Input:  d_in[0] = root_cubes f32 [B=32, X=128, Y=128, Z=64]
// Output: d_out   = f32 [B, 10, 5] = (x,y,z, valid-1, score)
// ws: 32*128*10*8 = 327,680 bytes of partial top-10 keys.

#define TPB 256
#define XT 16
#define YT 8
#define HX (XT + 2)          // 18
#define HY (YT + 2)          // 10
#define NCOL (HX * HY)       // 180 columns
#define CSTR 65              // padded column stride in floats (bank-coprime)
#define CAND_CAP 2048
#define NK 10
#define TILES_X 8
#define TILES_Y 16
#define TILES_PER_B (TILES_X * TILES_Y)  // 128

__device__ __forceinline__ unsigned long long wave_max_u64(unsigned long long v) {
#pragma unroll
  for (int off = 32; off > 0; off >>= 1) {
    unsigned long long o = __shfl_down(v, (unsigned)off, 64);
    if (o > v) v = o;
  }
  return v;
}

__global__ __launch_bounds__(TPB) void peaks_topk_partial(
    const float* __restrict__ in, unsigned long long* __restrict__ part) {
  __shared__ float tile[NCOL * CSTR];              // 46,800 B
  __shared__ unsigned long long cand[CAND_CAP];    // 16,384 B
  __shared__ unsigned long long red4[TPB / 64];
  __shared__ int cnt;

  const int tid = threadIdx.x;
  const int tx = blockIdx.x, ty = blockIdx.y, b = blockIdx.z;
  const int x0 = tx * XT, y0 = ty * YT;
  if (tid == 0) cnt = 0;

  // ---- stage halo tile (clamped coords == -inf padding for max) ----
  const float* __restrict__ src = in + (size_t)b * (128 * 128 * 64);
#pragma unroll 1
  for (int i = tid; i < NCOL * 64; i += TPB) {
    int xo = i / (HY * 64);
    int rem = i - xo * (HY * 64);
    int yo = rem >> 6;
    int z = rem & 63;
    int gx = x0 - 1 + xo; gx = max(0, min(127, gx));
    int gy = y0 - 1 + yo; gy = max(0, min(127, gy));
    tile[(xo * HY + yo) * CSTR + z] = src[(((gx << 7) | gy) << 6) | z];
  }
  __syncthreads();

  // ---- separable 27-max via z-rotation of max9 planes ----
  {
    const int c = tid & 127;
    const int xl = c >> 3;               // 0..15
    const int yl = c & 7;                // 0..7
    const int z0 = (tid >> 7) << 5;      // 0 or 32
    const int base = (xl * HY + yl) * CSTR;
    const int own = ((xl + 1) * HY + (yl + 1)) * CSTR;

    auto max9 = [&](int z) -> float {
      float m = -1e30f;
#pragma unroll
      for (int dx = 0; dx < 3; ++dx)
#pragma unroll
        for (int dy = 0; dy < 3; ++dy)
          m = fmaxf(m, tile[base + (dx * HY + dy) * CSTR + z]);
      return m;
    };

    float mp = (z0 == 0) ? -1e30f : max9(z0 - 1);
    float mc = max9(z0);
#pragma unroll 1
    for (int z = z0; z < z0 + 32; ++z) {
      float mn = (z == 63) ? -1e30f : max9(z + 1);
      float w = fmaxf(mp, fmaxf(mc, mn));
      float v = tile[own + z];
      if (v >= w) {  // v == pooled max  (max27 includes v)
        unsigned g = ((unsigned)(x0 + xl) << 13) | ((unsigned)(y0 + yl) << 6) |
                     (unsigned)z;
        unsigned long long key =
            ((unsigned long long)__float_as_uint(v) << 32) |
            (unsigned long long)(unsigned)(~g);
        int s = atomicAdd(&cnt, 1);
        if (s < CAND_CAP) cand[s] = key;
      }
      mp = mc; mc = mn;
    }
  }
  __syncthreads();

  const int count = min(cnt, CAND_CAP);
  unsigned long long* __restrict__ outp =
      part + ((size_t)b * TILES_PER_B + (size_t)(ty * TILES_X + tx)) * NK;

  // ---- 10 argmax rounds (keys unique -> winner identified by equality) ----
  for (int r = 0; r < NK; ++r) {
    unsigned long long best = 0ull; int bslot = -1;
    for (int i = tid; i < count; i += TPB)
      if (cand[i] > best) { best = cand[i]; bslot = i; }
    unsigned long long wmax = wave_max_u64(best);
    if ((tid & 63) == 0) red4[tid >> 6] = wmax;
    __syncthreads();
    unsigned long long win = red4[0];
#pragma unroll
    for (int k = 1; k < TPB / 64; ++k) if (red4[k] > win) win = red4[k];
    if (win != 0ull && best == win && bslot >= 0) cand[bslot] = 0ull;
    if (tid == 0) outp[r] = win;
    __syncthreads();
  }
}

__global__ __launch_bounds__(TPB) void final_select(
    const unsigned long long* __restrict__ part, float* __restrict__ out) {
  __shared__ unsigned long long cand[TILES_PER_B * NK];  // 1280 keys
  __shared__ unsigned long long red4[TPB / 64];
  const int tid = threadIdx.x;
  const int b = blockIdx.x;

  const unsigned long long* __restrict__ src = part + (size_t)b * TILES_PER_B * NK;
  for (int i = tid; i < TILES_PER_B * NK; i += TPB) cand[i] = src[i];
  __syncthreads();

  for (int r = 0; r < NK; ++r) {
    unsigned long long best = 0ull; int bslot = -1;
    for (int i = tid; i < TILES_PER_B * NK; i += TPB)
      if (cand[i] > best) { best = cand[i]; bslot = i; }
    unsigned long long wmax = wave_max_u64(best);
    if ((tid & 63) == 0) red4[tid >> 6] = wmax;
    __syncthreads();
    unsigned long long win = red4[0];
#pragma unroll
    for (int k = 1; k < TPB / 64; ++k) if (red4[k] > win) win = red4[k];
    if (win != 0ull && best == win && bslot >= 0) cand[bslot] = 0ull;
    if (tid == 0) {
      float val = 0.0f; unsigned g = 0u;
      if (win != 0ull) {
        val = __uint_as_float((unsigned)(win >> 32));
        g = ~((unsigned)win);
      }
      float fx = (float)(g >> 13) * (8000.0f / 127.0f) - 4000.0f;
      float fy = (float)((g >> 6) & 127u) * (8000.0f / 127.0f) - 4000.0f;
      float fz = (float)(g & 63u) * (2000.0f / 63.0f) - 700.0f;
      float conf = (val > 0.3f) ? 0.0f : -1.0f;
      float* o = out + ((size_t)b * NK + r) * 5;
      o[0] = fx; o[1] = fy; o[2] = fz; o[3] = conf; o[4] = val;
    }
    __syncthreads();
  }
}

extern "C" void kernel_launch(void* const* d_in, const int* in_sizes, int n_in,
                              void* d_out, int out_size, void* d_ws, size_t ws_size,
                              hipStream_t stream) {
  const float* in = (const float*)d_in[0];
  float* out = (float*)d_out;
  unsigned long long* part = (unsigned long long*)d_ws;  // 327,680 B used

  const int B = in_sizes[0] >> 20;  // elements per batch = 128*128*64 = 2^20
  dim3 gridA(TILES_X, TILES_Y, (unsigned)B);
  peaks_topk_partial<<<gridA, dim3(TPB), 0, stream>>>(in, part);
  final_select<<<dim3((unsigned)B), dim3(TPB), 0, stream>>>(part, out);
}

// Round 2
// 280.300 us; speedup vs baseline: 1.3539x; 1.3539x over previous
//
#include <hip/hip_runtime.h>
#include <stdint.h>

// ProposalLayerSoft: 3x3x3 NMS + per-batch top-10 + coord epilogue.
// Input:  d_in[0] = root_cubes f32 [B=32, X=128, Y=128, Z=64]
// Output: d_out   = f32 [B, 10, 5] = (x,y,z, valid-1, score)
// ws: 32*128*10*8 = 327,680 bytes of per-tile top-10 keys.

#define TPB 256
#define XT 16
#define YT 8
#define HX 18
#define HY 10
#define NCOL (HX * HY)       // 180 halo columns
#define CSTR 68              // floats; 16B-aligned pad (272 B), 2-way banks only
#define NK 10
#define TILES_X 8
#define TILES_Y 16
#define TILES_PER_B (TILES_X * TILES_Y)  // 128
#define WCAP 128             // per-wave candidate cap (expected ~76, 6 sigma)

typedef unsigned long long u64;

__device__ __forceinline__ u64 bfly_max_u64(u64 v) {
#pragma unroll
  for (int off = 1; off < 64; off <<= 1) {
    u64 o = __shfl_xor(v, off, 64);
    v = (o > v) ? o : v;
  }
  return v;
}

__device__ __forceinline__ float4 fmax4(float4 a, float4 b) {
  return make_float4(fmaxf(a.x, b.x), fmaxf(a.y, b.y),
                     fmaxf(a.z, b.z), fmaxf(a.w, b.w));
}

__global__ __launch_bounds__(TPB, 3) void peaks_topk(
    const float* __restrict__ in, u64* __restrict__ part) {
  __shared__ __align__(16) float tile[NCOL * CSTR];  // 48,960 B
  __shared__ u64 cand[4 * WCAP];                     //  4,096 B
  __shared__ int cnt[4];
  __shared__ u64 wtop[4 * NK];

  const int tid = threadIdx.x;
  const int tx = blockIdx.x, ty = blockIdx.y, b = blockIdx.z;
  const int x0 = tx * XT, y0 = ty * YT;
  const int w = tid >> 6, lane = tid & 63;

  cand[w * WCAP + lane] = 0;
  cand[w * WCAP + 64 + lane] = 0;
  if (lane == 0) cnt[w] = 0;

  // ---- stage halo tile, float4 (16 lanes = one contiguous 256B column) ----
  const float* __restrict__ src = in + ((size_t)b << 20);
#pragma unroll 1
  for (int i = tid; i < NCOL * 16; i += TPB) {
    int col = i >> 4, zq = i & 15;
    int xo = col / HY;
    int yo = col - xo * HY;
    int gx = min(127, max(0, x0 - 1 + xo));
    int gy = min(127, max(0, y0 - 1 + yo));
    float4 v = *(const float4*)(src + (((gx << 7) | gy) << 6) + (zq << 2));
    *(float4*)(tile + col * CSTR + (zq << 2)) = v;
  }
  __syncthreads();

  // ---- 27-max: per-chunk max9 (9 x ds_read_b128) + z-rotation pipeline ----
  {
    const int h = tid >> 7;            // z-half: waves 0,1 -> 0; waves 2,3 -> 1
    const int c = tid & 127;
    const int xl = c >> 3, yl = c & 7;
    const float* base = tile + (xl * HY + yl) * CSTR;

    auto rd = [&](int dx, int dy, int q) -> float4 {
      return *(const float4*)(base + (dx * HY + dy) * CSTR + (q << 2));
    };
    auto max9q = [&](int q, float4& vc) -> float4 {
      float4 m = rd(0, 0, q);
      m = fmax4(m, rd(0, 1, q));
      m = fmax4(m, rd(0, 2, q));
      m = fmax4(m, rd(1, 0, q));
      vc = rd(1, 1, q);                 // center column raw values
      m = fmax4(m, vc);
      m = fmax4(m, rd(1, 2, q));
      m = fmax4(m, rd(2, 0, q));
      m = fmax4(m, rd(2, 1, q));
      m = fmax4(m, rd(2, 2, q));
      return m;
    };

    const int q0 = h << 3;  // chunk range [q0, q0+8)
    float prevlast;
    if (h == 0) {
      prevlast = -1e30f;
    } else {  // max9 at z=31 (last element of chunk 7)
      float m = -1e30f;
#pragma unroll
      for (int dx = 0; dx < 3; ++dx)
#pragma unroll
        for (int dy = 0; dy < 3; ++dy)
          m = fmaxf(m, base[(dx * HY + dy) * CSTR + 31]);
      prevlast = m;
    }

    float4 vc;
    float4 m9c = max9q(q0, vc);
#pragma unroll 2
    for (int q = q0; q < q0 + 8; ++q) {
      float4 vn = make_float4(-1e30f, -1e30f, -1e30f, -1e30f);
      float4 m9n = vn;
      if (q < 15) m9n = max9q(q + 1, vn);
      float4 w27;
      w27.x = fmaxf(prevlast, fmaxf(m9c.x, m9c.y));
      w27.y = fmaxf(m9c.x, fmaxf(m9c.y, m9c.z));
      w27.z = fmaxf(m9c.y, fmaxf(m9c.z, m9c.w));
      w27.w = fmaxf(m9c.z, fmaxf(m9c.w, m9n.x));
      const int zb = q << 2;
      const float* vcp = &vc.x;
      const float* wp = &w27.x;
#pragma unroll
      for (int j = 0; j < 4; ++j) {
        float v = vcp[j];
        if (v >= wp[j]) {  // v == 27-neighborhood max -> local peak
          unsigned g = ((unsigned)(x0 + xl) << 13) |
                       ((unsigned)(y0 + yl) << 6) | (unsigned)(zb + j);
          u64 key = ((u64)__float_as_uint(v) << 32) | (u64)(unsigned)(~g);
          int s = atomicAdd(&cnt[w], 1);
          if (s < WCAP) cand[w * WCAP + s] = key;
        }
      }
      prevlast = m9c.w;
      m9c = m9n;
      vc = vn;
    }
  }

  // ---- per-wave top-10 (register slots + butterfly, no barriers) ----
  {
    __builtin_amdgcn_s_waitcnt(0);  // drain LDS writes (same-wave visibility)
    u64 c0 = cand[w * WCAP + lane];
    u64 c1 = cand[w * WCAP + 64 + lane];
    u64 mine = 0;
#pragma unroll 1
    for (int r = 0; r < NK; ++r) {
      u64 best = (c0 > c1) ? c0 : c1;
      u64 m = bfly_max_u64(best);
      if (m != 0 && best == m) {  // unique keys: exactly one lane clears
        if (c0 == m) c0 = 0; else c1 = 0;
      }
      if (lane == r) mine = m;
    }
    if (lane < NK) wtop[w * NK + lane] = mine;
  }
  __syncthreads();

  // ---- wave 0 merges 40 -> 10, writes tile result ----
  if (w == 0) {
    u64 c0 = (lane < 4 * NK) ? wtop[lane] : 0;
    u64 mine = 0;
#pragma unroll 1
    for (int r = 0; r < NK; ++r) {
      u64 m = bfly_max_u64(c0);
      if (m != 0 && c0 == m) c0 = 0;
      if (lane == r) mine = m;
    }
    if (lane < NK)
      part[((size_t)b * TILES_PER_B + (size_t)(ty * TILES_X + tx)) * NK + lane] =
          mine;
  }
}

__global__ __launch_bounds__(TPB) void final_select(
    const u64* __restrict__ part, float* __restrict__ out) {
  __shared__ u64 cand[TILES_PER_B * NK];  // 1280 keys
  __shared__ u64 red4[4];
  const int tid = threadIdx.x;
  const int b = blockIdx.x;
  const int w = tid >> 6, lane = tid & 63;

  const u64* __restrict__ src = part + (size_t)b * (TILES_PER_B * NK);
  for (int i = tid; i < TILES_PER_B * NK; i += TPB) cand[i] = src[i];
  __syncthreads();

  for (int r = 0; r < NK; ++r) {
    u64 best = 0;
    int slot = -1;
#pragma unroll
    for (int k = 0; k < (TILES_PER_B * NK) / TPB; ++k) {
      int i = tid + k * TPB;
      if (cand[i] > best) { best = cand[i]; slot = i; }
    }
    u64 wm = bfly_max_u64(best);
    if (lane == 0) red4[w] = wm;
    __syncthreads();
    u64 win = red4[0];
#pragma unroll
    for (int k = 1; k < 4; ++k) win = (red4[k] > win) ? red4[k] : win;
    if (win != 0 && best == win && slot >= 0) cand[slot] = 0;
    if (tid == 0) {
      float val = 0.0f;
      unsigned g = 0u;
      if (win != 0) {
        val = __uint_as_float((unsigned)(win >> 32));
        g = ~((unsigned)win);
      }
      float fx = (float)(g >> 13) * (8000.0f / 127.0f) - 4000.0f;
      float fy = (float)((g >> 6) & 127u) * (8000.0f / 127.0f) - 4000.0f;
      float fz = (float)(g & 63u) * (2000.0f / 63.0f) - 700.0f;
      float conf = (val > 0.3f) ? 0.0f : -1.0f;
      float* o = out + ((size_t)b * NK + r) * 5;
      o[0] = fx; o[1] = fy; o[2] = fz; o[3] = conf; o[4] = val;
    }
    __syncthreads();
  }
}

extern "C" void kernel_launch(void* const* d_in, const int* in_sizes, int n_in,
                              void* d_out, int out_size, void* d_ws, size_t ws_size,
                              hipStream_t stream) {
  const float* in = (const float*)d_in[0];
  float* out = (float*)d_out;
  u64* part = (u64*)d_ws;  // 327,680 B used

  const int B = in_sizes[0] >> 20;  // 128*128*64 = 2^20 elements per batch
  dim3 gridA(TILES_X, TILES_Y, (unsigned)B);
  peaks_topk<<<gridA, dim3(TPB), 0, stream>>>(in, part);
  final_select<<<dim3((unsigned)B), dim3(TPB), 0, stream>>>(part, out);
}

// Round 3
// 241.453 us; speedup vs baseline: 1.5718x; 1.1609x over previous
//
#include <hip/hip_runtime.h>
#include <stdint.h>

// ProposalLayerSoft: 3x3x3 NMS + per-batch top-10 + coord epilogue.
// Input:  d_in[0] = root_cubes f32 [B=32, X=128, Y=128, Z=64]
// Output: d_out   = f32 [B, 10, 5] = (x,y,z, valid-1, score)
// ws: 32*100*10*8 = 256,000 bytes of per-tile top-10 keys.
//
// Design: one thread = one (x,y) z-column held in registers (float4 chunks).
// Separable 27-max: z-stage in registers, y-stage via in-wave shfl (lane =
// (x&3)*16 + y, so y+-1 is lane+-1), x-stage via a tiny double-buffered LDS
// plane (2 contiguous b128 writes + 4 reads per 8-z chunk, conflict-free).

#define TPB 256
#define IT 14                 // interior tile dim (x and y)
#define TILES 10              // ceil(128/14)
#define NK 10
#define WCAP 256              // per-wave candidate cap (mean ~135, +10 sigma)
typedef unsigned long long u64;

__device__ __forceinline__ u64 bfly_max_u64(u64 v) {
#pragma unroll
  for (int off = 1; off < 64; off <<= 1) {
    u64 o = __shfl_xor(v, off, 64);
    v = (o > v) ? o : v;
  }
  return v;
}

__global__ __launch_bounds__(TPB, 5) void peaks_topk(
    const float* __restrict__ in, u64* __restrict__ part) {
  __shared__ __align__(16) float4 ymb[2][2][TPB];  // 16 KB, double-buffered
  __shared__ u64 cand[4][WCAP];                    //  8 KB
  __shared__ int cnt[4];
  __shared__ u64 wtop[4 * NK];

  const int tid = threadIdx.x;
  const int x = tid >> 4, y = tid & 15;            // 16x16 halo tile
  const int w = tid >> 6, lane = tid & 63;         // lane = (x&3)*16 + y
  const int bx = blockIdx.x, by = blockIdx.y, b = blockIdx.z;

  if (lane == 0) cnt[w] = 0;
#pragma unroll
  for (int i = 0; i < WCAP / 64; ++i) cand[w][lane + 64 * i] = 0;

  const int gx = bx * IT + x - 1;
  const int gy = by * IT + y - 1;
  const int cx = min(127, max(0, gx));             // clamp == -inf pad for max
  const int cy = min(127, max(0, gy));
  const float* __restrict__ col =
      in + ((size_t)b << 20) + (size_t)(((cx << 7) | cy) << 6);
  const bool interior =
      (x >= 1) && (x <= IT) && (y >= 1) && (y <= IT) && (gx <= 127) && (gy <= 127);

  float4 cur0 = *(const float4*)(col);
  float4 cur1 = *(const float4*)(col + 4);
  float prev_last = -1e30f;                        // v[z-1] below this chunk

#pragma unroll 1
  for (int q = 0; q < 8; ++q) {
    float4 nxt0, nxt1;
    if (q < 7) {
      nxt0 = *(const float4*)(col + (q + 1) * 8);
      nxt1 = *(const float4*)(col + (q + 1) * 8 + 4);
    } else {
      nxt0 = make_float4(-1e30f, -1e30f, -1e30f, -1e30f);
      nxt1 = nxt0;
    }
    float v[8] = {cur0.x, cur0.y, cur0.z, cur0.w,
                  cur1.x, cur1.y, cur1.z, cur1.w};
    // ---- z-stage (registers only) ----
    float zm[8];
    zm[0] = fmaxf(prev_last, fmaxf(v[0], v[1]));
#pragma unroll
    for (int j = 1; j < 7; ++j) zm[j] = fmaxf(v[j - 1], fmaxf(v[j], v[j + 1]));
    zm[7] = fmaxf(v[6], fmaxf(v[7], nxt0.x));
    // ---- y-stage via in-wave shuffles (edges produce garbage, unused) ----
    float ym[8];
#pragma unroll
    for (int j = 0; j < 8; ++j) {
      float a = __shfl_up(zm[j], 1, 64);
      float c = __shfl_down(zm[j], 1, 64);
      ym[j] = fmaxf(zm[j], fmaxf(a, c));
    }
    // ---- x-stage via LDS plane ----
    const int buf = q & 1;
    ymb[buf][0][tid] = make_float4(ym[0], ym[1], ym[2], ym[3]);
    ymb[buf][1][tid] = make_float4(ym[4], ym[5], ym[6], ym[7]);
    __syncthreads();
    if (interior) {
      float4 a0 = ymb[buf][0][tid - 16];
      float4 b0 = ymb[buf][0][tid + 16];
      float4 a1 = ymb[buf][1][tid - 16];
      float4 b1 = ymb[buf][1][tid + 16];
      float am[8] = {a0.x, a0.y, a0.z, a0.w, a1.x, a1.y, a1.z, a1.w};
      float bm[8] = {b0.x, b0.y, b0.z, b0.w, b1.x, b1.y, b1.z, b1.w};
#pragma unroll
      for (int j = 0; j < 8; ++j) {
        float m27 = fmaxf(ym[j], fmaxf(am[j], bm[j]));
        if (v[j] >= m27) {  // v == 27-neighborhood max -> local peak
          unsigned g = ((unsigned)gx << 13) | ((unsigned)gy << 6) |
                       (unsigned)(q * 8 + j);
          u64 key = ((u64)__float_as_uint(v[j]) << 32) | (u64)(unsigned)(~g);
          int s = atomicAdd(&cnt[w], 1);
          if (s < WCAP) cand[w][s] = key;
        }
      }
    }
    prev_last = v[7];
    cur0 = nxt0;
    cur1 = nxt1;
  }

  // ---- per-wave top-10 (register slots + butterfly, no barriers) ----
  {
    __builtin_amdgcn_s_waitcnt(0);  // drain own-wave LDS writes
    u64 c0 = cand[w][lane];
    u64 c1 = cand[w][lane + 64];
    u64 c2 = cand[w][lane + 128];
    u64 c3 = cand[w][lane + 192];
    u64 mine = 0;
#pragma unroll 1
    for (int r = 0; r < NK; ++r) {
      u64 b01 = (c0 > c1) ? c0 : c1;
      u64 b23 = (c2 > c3) ? c2 : c3;
      u64 best = (b01 > b23) ? b01 : b23;
      u64 m = bfly_max_u64(best);
      if (m != 0 && best == m) {  // unique keys: exactly one lane+slot clears
        if (c0 == m) c0 = 0;
        else if (c1 == m) c1 = 0;
        else if (c2 == m) c2 = 0;
        else c3 = 0;
      }
      if (lane == r) mine = m;
    }
    if (lane < NK) wtop[w * NK + lane] = mine;
  }
  __syncthreads();

  // ---- wave 0 merges 40 -> 10, writes tile result ----
  if (w == 0) {
    u64 c0 = (lane < 4 * NK) ? wtop[lane] : 0;
    u64 mine = 0;
#pragma unroll 1
    for (int r = 0; r < NK; ++r) {
      u64 m = bfly_max_u64(c0);
      if (m != 0 && c0 == m) c0 = 0;
      if (lane == r) mine = m;
    }
    if (lane < NK)
      part[((size_t)b * (TILES * TILES) + (size_t)(by * TILES + bx)) * NK +
           lane] = mine;
  }
}

__global__ __launch_bounds__(TPB) void final_select(
    const u64* __restrict__ part, float* __restrict__ out) {
  __shared__ u64 cand[1024];  // 1000 keys padded to 1024
  __shared__ u64 red4[4];
  const int tid = threadIdx.x;
  const int b = blockIdx.x;
  const int w = tid >> 6, lane = tid & 63;
  const int NKEY = TILES * TILES * NK;  // 1000

  const u64* __restrict__ src = part + (size_t)b * NKEY;
  for (int i = tid; i < 1024; i += TPB) cand[i] = (i < NKEY) ? src[i] : 0;
  __syncthreads();

  for (int r = 0; r < NK; ++r) {
    u64 best = 0;
    int slot = -1;
#pragma unroll
    for (int k = 0; k < 4; ++k) {
      int i = tid + k * TPB;
      if (cand[i] > best) { best = cand[i]; slot = i; }
    }
    u64 wm = bfly_max_u64(best);
    if (lane == 0) red4[w] = wm;
    __syncthreads();
    u64 win = red4[0];
#pragma unroll
    for (int k = 1; k < 4; ++k) win = (red4[k] > win) ? red4[k] : win;
    if (win != 0 && best == win && slot >= 0) cand[slot] = 0;
    if (tid == 0) {
      float val = 0.0f;
      unsigned g = 0u;
      if (win != 0) {
        val = __uint_as_float((unsigned)(win >> 32));
        g = ~((unsigned)win);
      }
      float fx = (float)(g >> 13) * (8000.0f / 127.0f) - 4000.0f;
      float fy = (float)((g >> 6) & 127u) * (8000.0f / 127.0f) - 4000.0f;
      float fz = (float)(g & 63u) * (2000.0f / 63.0f) - 700.0f;
      float conf = (val > 0.3f) ? 0.0f : -1.0f;
      float* o = out + ((size_t)b * NK + r) * 5;
      o[0] = fx; o[1] = fy; o[2] = fz; o[3] = conf; o[4] = val;
    }
    __syncthreads();
  }
}

extern "C" void kernel_launch(void* const* d_in, const int* in_sizes, int n_in,
                              void* d_out, int out_size, void* d_ws, size_t ws_size,
                              hipStream_t stream) {
  const float* in = (const float*)d_in[0];
  float* out = (float*)d_out;
  u64* part = (u64*)d_ws;  // 256,000 B used

  const int B = in_sizes[0] >> 20;  // 128*128*64 = 2^20 elements per batch
  dim3 gridA(TILES, TILES, (unsigned)B);
  peaks_topk<<<gridA, dim3(TPB), 0, stream>>>(in, part);
  final_select<<<dim3((unsigned)B), dim3(TPB), 0, stream>>>(part, out);
}